// Round 1
// baseline (489.692 us; speedup 1.0000x reference)
//
#include <hip/hip_runtime.h>
#include <hip/hip_bf16.h>

#define NB   64
#define NT   2048
#define NENC 512
#define NDEC 1024
#define NCONV 32
#define NK   31
#define NHID 256
#define NPAD 15

typedef __attribute__((ext_vector_type(8))) short bf16x8;  // 8 bf16 in 4 VGPRs
typedef __attribute__((ext_vector_type(4))) float f32x4;

// ws layout (bytes):
//   0      : W_sw    16 ntile x 16 kstep x 64 lane x 8 bf16 = 262144
//   262144 : G_sw    16 ntile x 64 lane x 8 bf16            = 16384
//   278528 : dec_proj 64 x 256 f32                           = 65536
#define WS_WSW 0
#define WS_GSW 262144
#define WS_DEC 278528

__device__ __forceinline__ short f2b(float f) {  // f32 -> bf16 (RNE)
  unsigned u = __builtin_bit_cast(unsigned, f);
  u += 0x7FFFu + ((u >> 16) & 1u);
  return (short)(u >> 16);
}

// ---------------------------------------------------------------- prep ------
// blocks [0,512): W_enc -> bf16 fragments in exact MFMA B-operand order
// blocks [512,544): G[h,k] = sum_c W_att[h,c]*conv_w[c,k] -> B-frag order
// blocks [544,608): dec_proj[b,h] = dec_state[b,:] . W_dec[h,:]
__global__ __launch_bounds__(256) void prep_kernel(
    const float* __restrict__ W_enc, const float* __restrict__ W_att,
    const float* __restrict__ conv_w, const float* __restrict__ dec_state,
    const float* __restrict__ W_dec, char* __restrict__ ws)
{
  const int tid = threadIdx.x;
  const int blk = blockIdx.x;
  if (blk < 512) {
    int idx = blk * 256 + tid;                       // [0, 131072)
    int j = idx & 7, lane = (idx >> 3) & 63;
    int ks = (idx >> 9) & 15, nt = idx >> 13;
    int h = nt * 16 + (lane & 15);
    int k = ks * 32 + (lane >> 4) * 8 + j;
    ((short*)(ws + WS_WSW))[idx] = f2b(W_enc[h * NENC + k]);
  } else if (blk < 544) {
    int idx = (blk - 512) * 256 + tid;               // [0, 8192)
    int j = idx & 7, lane = (idx >> 3) & 63, nt = idx >> 9;
    int h = nt * 16 + (lane & 15);
    int k = (lane >> 4) * 8 + j;
    float v = 0.f;
    if (k < NK) {
      for (int c = 0; c < NCONV; ++c)
        v += W_att[h * NCONV + c] * conv_w[c * NK + k];
    }
    ((short*)(ws + WS_GSW))[idx] = f2b(v);
  } else {
    int idx = (blk - 544) * 256 + tid;               // [0, 16384)
    int h = idx & 255, b = idx >> 8;
    const float4* ds4 = (const float4*)(dec_state + b * NDEC);
    const float4* wd4 = (const float4*)(W_dec + h * NDEC);
    float s = 0.f;
    for (int d = 0; d < NDEC / 4; ++d) {
      float4 a = ds4[d], w = wd4[d];
      s += a.x * w.x + a.y * w.y + a.z * w.z + a.w * w.w;
    }
    ((float*)(ws + WS_DEC))[idx] = s;
  }
}

// -------------------------------------------------------------- energy ------
// block = 256 thr (4 waves), tile M=64 (t), N=256 (h), K=512.
// wave w: cols [64w, 64w+64) as 4 ntiles, rows [0,64) as 4 mtiles (4x4 frags).
// acc initialized by conv MFMA (P-window x G), K-loop adds enc x W_enc^T,
// epilogue adds dec_proj + b_enc, tanh, dot w_w, reduce -> energy[b,t].
__global__ __launch_bounds__(256, 2) void energy_kernel(
    const float* __restrict__ enc, const float* __restrict__ prev,
    const int* __restrict__ text_len, const float* __restrict__ b_enc,
    const float* __restrict__ w_w, const float* __restrict__ w_b,
    const char* __restrict__ ws, float* __restrict__ e_out)
{
  const int b = blockIdx.y;
  const int t0 = blockIdx.x * 64;
  if (t0 >= text_len[b]) return;   // masked region: softmax ignores it

  __shared__ short As[64][512];    // exactly 64 KB, chunk-XOR-swizzled

  const int tid = threadIdx.x;
  const int wave = tid >> 6, lane = tid & 63;
  const int col = lane & 15, quad = lane >> 4;

  const short* Wsw = (const short*)(ws + WS_WSW);
  const short* Gsw = (const short*)(ws + WS_GSW);
  const float* dec_proj = (const float*)(ws + WS_DEC);

  // ---- conv init: acc[mt][i] = P_frag(mt) x G_frag(i) ----
  f32x4 acc[4][4];
  {
    bf16x8 gf[4];
#pragma unroll
    for (int i = 0; i < 4; ++i)
      gf[i] = ((const bf16x8*)Gsw)[(wave * 4 + i) * 64 + lane];
    const float* pb = prev + b * NT;
#pragma unroll
    for (int mt = 0; mt < 4; ++mt) {
      int t = t0 + mt * 16 + col;          // A-operand row m = lane&15
      bf16x8 pf;
#pragma unroll
      for (int j = 0; j < 8; ++j) {
        int k = quad * 8 + j;              // A-operand k = quad*8+j
        int ti = t + k - NPAD;
        float v = (k < NK && ti >= 0 && ti < NT) ? pb[ti] : 0.f;
        pf[j] = f2b(v);
      }
      f32x4 z = {0.f, 0.f, 0.f, 0.f};
#pragma unroll
      for (int i = 0; i < 4; ++i)
        acc[mt][i] = __builtin_amdgcn_mfma_f32_16x16x32_bf16(pf, gf[i], z, 0, 0, 0);
    }
  }

  // ---- stage A tile 64x512 f32 -> bf16 LDS (chunk-of-8 XOR swizzle) ----
  {
    const float* src = enc + ((size_t)b * NT + t0) * NENC;
#pragma unroll 4
    for (int it = 0; it < 16; ++it) {
      int cidx = it * 256 + tid;
      int row = cidx >> 6;                 // one row per 64 consecutive chunks
      int c   = cidx & 63;                 // chunk of 8 floats
      const float4* p = (const float4*)(src + row * NENC + c * 8);
      float4 v0 = p[0], v1 = p[1];
      bf16x8 o;
      o[0] = f2b(v0.x); o[1] = f2b(v0.y); o[2] = f2b(v0.z); o[3] = f2b(v0.w);
      o[4] = f2b(v1.x); o[5] = f2b(v1.y); o[6] = f2b(v1.z); o[7] = f2b(v1.w);
      int csw = c ^ (row & 7);             // bank-spread: 2-way max (free)
      *(bf16x8*)(&As[row][csw * 8]) = o;
    }
  }
  __syncthreads();

  // ---- main K loop: 16 steps of K=32 ----
#pragma unroll 2
  for (int ks = 0; ks < 16; ++ks) {
    bf16x8 bf[4];
#pragma unroll
    for (int i = 0; i < 4; ++i)            // coalesced 1KB L2-hot loads
      bf[i] = ((const bf16x8*)Wsw)[((wave * 4 + i) * 16 + ks) * 64 + lane];
#pragma unroll
    for (int mt = 0; mt < 4; ++mt) {
      int row = mt * 16 + col;
      int chunk = (ks * 4 + quad) ^ (row & 7);
      bf16x8 af = *(const bf16x8*)(&As[row][chunk * 8]);
#pragma unroll
      for (int i = 0; i < 4; ++i)
        acc[mt][i] = __builtin_amdgcn_mfma_f32_16x16x32_bf16(af, bf[i], acc[mt][i], 0, 0, 0);
    }
  }

  __syncthreads();                         // done reading As; reuse as ep[]
  float* ep = (float*)&As[0][0];           // ep[wave*64 + t_local]

  // ---- epilogue: tanh, dot w_w, reduce over h ----
  const float* dpb = dec_proj + b * NHID;
#pragma unroll
  for (int mt = 0; mt < 4; ++mt) {
#pragma unroll
    for (int r = 0; r < 4; ++r) {          // C/D: row = quad*4+r, col = lane&15
      float s = 0.f;
#pragma unroll
      for (int i = 0; i < 4; ++i) {
        int h = (wave * 4 + i) * 16 + col;
        float x = acc[mt][i][r] + dpb[h] + b_enc[h];
        float e2 = __expf(2.f * x);        // tanh(x) = (e^2x-1)/(e^2x+1)
        s += w_w[h] * ((e2 - 1.f) / (e2 + 1.f));
      }
      s += __shfl_xor(s, 1);               // reduce 16 lanes of the quad
      s += __shfl_xor(s, 2);
      s += __shfl_xor(s, 4);
      s += __shfl_xor(s, 8);
      if (col == 0) ep[wave * 64 + mt * 16 + quad * 4 + r] = s;
    }
  }
  __syncthreads();
  if (tid < 64) {                          // sum the 4 waves' h-partials
    float e = ep[tid] + ep[64 + tid] + ep[128 + tid] + ep[192 + tid] + w_b[0];
    e_out[b * NT + t0 + tid] = e;
  }
}

// ------------------------------------------------------------- softmax ------
// one block per b. Also zeroes the att_c region for the context atomics.
__global__ __launch_bounds__(256) void softmax_kernel(
    const int* __restrict__ text_len, float* __restrict__ d_out)
{
  const int b = blockIdx.x, tid = threadIdx.x;
  const int wave = tid >> 6, lane = tid & 63;
  __shared__ float red[4];

  d_out[b * NENC + tid] = 0.f;             // zero att_c[b, :]
  d_out[b * NENC + tid + 256] = 0.f;

  const int len = text_len[b];
  float* e = d_out + NB * NENC + b * NT;   // energies in-place -> att_w

  float ev[8];
#pragma unroll
  for (int j = 0; j < 8; ++j) ev[j] = e[tid + j * 256];

  float m = -3.0e38f;
#pragma unroll
  for (int j = 0; j < 8; ++j)
    if (tid + j * 256 < len) m = fmaxf(m, ev[j]);
#pragma unroll
  for (int o = 1; o < 64; o <<= 1) m = fmaxf(m, __shfl_xor(m, o));
  if (lane == 0) red[wave] = m;
  __syncthreads();
  m = fmaxf(fmaxf(red[0], red[1]), fmaxf(red[2], red[3]));
  __syncthreads();

  float p[8], sum = 0.f;
#pragma unroll
  for (int j = 0; j < 8; ++j) {
    p[j] = (tid + j * 256 < len) ? __expf(ev[j] - m) : 0.f;
    sum += p[j];
  }
#pragma unroll
  for (int o = 1; o < 64; o <<= 1) sum += __shfl_xor(sum, o);
  if (lane == 0) red[wave] = sum;
  __syncthreads();
  sum = red[0] + red[1] + red[2] + red[3];
  float inv = 1.f / sum;
#pragma unroll
  for (int j = 0; j < 8; ++j) e[tid + j * 256] = p[j] * inv;
}

// ------------------------------------------------------------- context ------
// att_c[b,c] = sum_t enc[b,t,c] * att_w[b,t]; 64-row chunks, skip masked.
__global__ __launch_bounds__(128) void context_kernel(
    const float* __restrict__ enc, const int* __restrict__ text_len,
    float* __restrict__ d_out)
{
  const int b = blockIdx.y;
  const int ts = blockIdx.x * 64;
  const int len = text_len[b];
  if (ts >= len) return;                   // att_w is exactly 0 there
  const int n = min(64, len - ts);
  const float* aw = d_out + NB * NENC + b * NT + ts;
  const float* ebase = enc + ((size_t)b * NT + ts) * NENC + threadIdx.x * 4;
  float4 acc = {0.f, 0.f, 0.f, 0.f};
  for (int t = 0; t < n; ++t) {
    float w = aw[t];
    float4 v = *(const float4*)(ebase + (size_t)t * NENC);
    acc.x += w * v.x; acc.y += w * v.y; acc.z += w * v.z; acc.w += w * v.w;
  }
  float* oc = d_out + b * NENC + threadIdx.x * 4;
  atomicAdd(oc + 0, acc.x);
  atomicAdd(oc + 1, acc.y);
  atomicAdd(oc + 2, acc.z);
  atomicAdd(oc + 3, acc.w);
}

// ------------------------------------------------------------------ launch --
extern "C" void kernel_launch(void* const* d_in, const int* in_sizes, int n_in,
                              void* d_out, int out_size, void* d_ws, size_t ws_size,
                              hipStream_t stream)
{
  const float* enc      = (const float*)d_in[0];
  const float* dec_st   = (const float*)d_in[1];
  const float* prev     = (const float*)d_in[2];
  const int*   text_len = (const int*)d_in[3];
  const float* W_enc    = (const float*)d_in[4];
  const float* b_enc    = (const float*)d_in[5];
  const float* W_dec    = (const float*)d_in[6];
  const float* W_att    = (const float*)d_in[7];
  const float* conv_w   = (const float*)d_in[8];
  const float* w_w      = (const float*)d_in[9];
  const float* w_b      = (const float*)d_in[10];
  float* out = (float*)d_out;
  char* ws = (char*)d_ws;

  hipLaunchKernelGGL(prep_kernel, dim3(608), dim3(256), 0, stream,
                     W_enc, W_att, conv_w, dec_st, W_dec, ws);
  hipLaunchKernelGGL(energy_kernel, dim3(32, 64), dim3(256), 0, stream,
                     enc, prev, text_len, b_enc, w_w, w_b, ws, out + NB * NENC);
  hipLaunchKernelGGL(softmax_kernel, dim3(64), dim3(256), 0, stream,
                     text_len, out);
  hipLaunchKernelGGL(context_kernel, dim3(32, 64), dim3(128), 0, stream,
                     enc, text_len, out);
}

// Round 2
// 431.715 us; speedup vs baseline: 1.1343x; 1.1343x over previous
//
#include <hip/hip_runtime.h>
#include <hip/hip_bf16.h>

#define NB   64
#define NT   2048
#define NENC 512
#define NDEC 1024
#define NCONV 32
#define NK   31
#define NHID 256
#define NPAD 15

typedef __attribute__((ext_vector_type(8))) short bf16x8;  // 8 bf16 in 4 VGPRs
typedef __attribute__((ext_vector_type(4))) float f32x4;

// ws layout (bytes):
//   0       : W_sw   16 nt x 16 ks x 64 lane x 8 bf16      = 262144
//   262144  : G_sw   16 nt x 64 lane x 8 bf16              = 16384
//   278528  : dec_proj 64 x 256 f32                        = 65536
//   344064  : ctx partials 64 b x 32 blk x 512 f32         = 4194304
//   4538368 : ml pairs 64 b x 32 blk x {m,l} f32           = 16384
#define WS_WSW 0
#define WS_GSW 262144
#define WS_DEC 278528
#define WS_CTX 344064
#define WS_ML  4538368

__device__ __forceinline__ short f2b(float f) {  // f32 -> bf16 (RNE)
  unsigned u = __builtin_bit_cast(unsigned, f);
  u += 0x7FFFu + ((u >> 16) & 1u);
  return (short)(u >> 16);
}
__device__ __forceinline__ float blo(unsigned u) {
  return __builtin_bit_cast(float, u << 16);
}
__device__ __forceinline__ float bhi(unsigned u) {
  return __builtin_bit_cast(float, u & 0xFFFF0000u);
}

// ---------------------------------------------------------------- prep ------
// blocks [0,512): W_enc -> bf16 fragments in exact MFMA B-operand order
// blocks [512,544): G[h,k] = sum_c W_att[h,c]*conv_w[c,k] -> B-frag order
// blocks [544,800): dec_proj[b,h], 4 threads per (b,h) (k-quarters)
__global__ __launch_bounds__(256) void prep_kernel(
    const float* __restrict__ W_enc, const float* __restrict__ W_att,
    const float* __restrict__ conv_w, const float* __restrict__ dec_state,
    const float* __restrict__ W_dec, char* __restrict__ ws)
{
  const int tid = threadIdx.x;
  const int blk = blockIdx.x;
  if (blk < 512) {
    int idx = blk * 256 + tid;                       // [0, 131072)
    int j = idx & 7, lane = (idx >> 3) & 63;
    int ks = (idx >> 9) & 15, nt = idx >> 13;
    int h = nt * 16 + (lane & 15);
    int k = ks * 32 + (lane >> 4) * 8 + j;
    ((short*)(ws + WS_WSW))[idx] = f2b(W_enc[h * NENC + k]);
  } else if (blk < 544) {
    int idx = (blk - 512) * 256 + tid;               // [0, 8192)
    int j = idx & 7, lane = (idx >> 3) & 63, nt = idx >> 9;
    int h = nt * 16 + (lane & 15);
    int k = (lane >> 4) * 8 + j;
    float v = 0.f;
    if (k < NK) {
      for (int c = 0; c < NCONV; ++c)
        v += W_att[h * NCONV + c] * conv_w[c * NK + k];
    }
    ((short*)(ws + WS_GSW))[idx] = f2b(v);
  } else {
    int idx = (blk - 544) * 256 + tid;               // [0, 65536)
    int bh = idx >> 2, q = idx & 3;                  // (b,h) + k-quarter
    int h = bh & 255, bb = bh >> 8;
    const float4* ds4 = (const float4*)(dec_state + bb * NDEC + q * 256);
    const float4* wd4 = (const float4*)(W_dec + h * NDEC + q * 256);
    float s = 0.f;
#pragma unroll 8
    for (int d = 0; d < 64; ++d) {
      float4 a = ds4[d], w = wd4[d];
      s += a.x * w.x + a.y * w.y + a.z * w.z + a.w * w.w;
    }
    s += __shfl_xor(s, 1);
    s += __shfl_xor(s, 2);
    if (q == 0) ((float*)(ws + WS_DEC))[bh] = s;
  }
}

// -------------------------------------------------------------- energy ------
// block = 256 thr (4 waves), tile M=64 (t), N=256 (h), K=512.
// Computes energies AND the flash-style per-block context partial from the
// resident LDS bf16 tile (no second enc pass). LDS = exactly 64 KB: the
// cross-wave reduce scratch lives in As row 0, saved to a register first
// (that saved uint is exactly the t=0 pair each thread needs in the
// context loop, so no restore is needed).
__global__ __launch_bounds__(256, 2) void energy_kernel(
    const float* __restrict__ enc, const float* __restrict__ prev,
    const int* __restrict__ text_len, const float* __restrict__ b_enc,
    const float* __restrict__ w_w, const float* __restrict__ w_b,
    char* __restrict__ ws, float* __restrict__ e_out)
{
  const int b = blockIdx.y;
  const int bx = blockIdx.x;
  const int t0 = bx * 64;
  const int len = text_len[b];
  if (t0 >= len) return;           // fully masked tile: contributes nothing

  __shared__ short As[64][512];    // 64 KB, chunk-XOR-swizzled

  const int tid = threadIdx.x;
  const int wave = tid >> 6, lane = tid & 63;
  const int col = lane & 15, quad = lane >> 4;

  const short* Wsw = (const short*)(ws + WS_WSW);
  const short* Gsw = (const short*)(ws + WS_GSW);
  const float* dec_proj = (const float*)(ws + WS_DEC);

  // ---- conv init: acc[mt][i] = P_frag(mt) x G_frag(i) ----
  f32x4 acc[4][4];
  {
    bf16x8 gf[4];
#pragma unroll
    for (int i = 0; i < 4; ++i)
      gf[i] = ((const bf16x8*)Gsw)[(wave * 4 + i) * 64 + lane];
    const float* pb = prev + b * NT;
#pragma unroll
    for (int mt = 0; mt < 4; ++mt) {
      int t = t0 + mt * 16 + col;          // A-operand row m = lane&15
      bf16x8 pf;
#pragma unroll
      for (int j = 0; j < 8; ++j) {
        int k = quad * 8 + j;              // A-operand k = quad*8+j
        int ti = t + k - NPAD;
        float v = (k < NK && ti >= 0 && ti < NT) ? pb[ti] : 0.f;
        pf[j] = f2b(v);
      }
      f32x4 z = {0.f, 0.f, 0.f, 0.f};
#pragma unroll
      for (int i = 0; i < 4; ++i)
        acc[mt][i] = __builtin_amdgcn_mfma_f32_16x16x32_bf16(pf, gf[i], z, 0, 0, 0);
    }
  }

  // ---- stage A tile 64x512 f32 -> bf16 LDS (chunk-of-8 XOR swizzle) ----
  {
    const float* src = enc + ((size_t)b * NT + t0) * NENC;
#pragma unroll 4
    for (int it = 0; it < 16; ++it) {
      int cidx = it * 256 + tid;
      int row = cidx >> 6;                 // one row per 64 consecutive chunks
      int c   = cidx & 63;                 // chunk of 8 floats
      const float4* p = (const float4*)(src + row * NENC + c * 8);
      float4 v0 = p[0], v1 = p[1];
      bf16x8 o;
      o[0] = f2b(v0.x); o[1] = f2b(v0.y); o[2] = f2b(v0.z); o[3] = f2b(v0.w);
      o[4] = f2b(v1.x); o[5] = f2b(v1.y); o[6] = f2b(v1.z); o[7] = f2b(v1.w);
      int csw = c ^ (row & 7);             // bank-spread: 2-way max (free)
      *(bf16x8*)(&As[row][csw * 8]) = o;
    }
  }
  __syncthreads();

  // ---- main K loop: 16 steps of K=32, B-frag software prefetch ----
  bf16x8 bcur[4];
#pragma unroll
  for (int i = 0; i < 4; ++i)
    bcur[i] = ((const bf16x8*)Wsw)[((wave * 4 + i) * 16 + 0) * 64 + lane];
#pragma unroll 2
  for (int ks = 0; ks < 16; ++ks) {
    bf16x8 bnxt[4];
    int ksn = (ks + 1) & 15;               // wrap: last prefetch harmless
#pragma unroll
    for (int i = 0; i < 4; ++i)
      bnxt[i] = ((const bf16x8*)Wsw)[((wave * 4 + i) * 16 + ksn) * 64 + lane];
#pragma unroll
    for (int mt = 0; mt < 4; ++mt) {
      int row = mt * 16 + col;
      int chunk = (ks * 4 + quad) ^ (row & 7);
      bf16x8 af = *(const bf16x8*)(&As[row][chunk * 8]);
#pragma unroll
      for (int i = 0; i < 4; ++i)
        acc[mt][i] = __builtin_amdgcn_mfma_f32_16x16x32_bf16(af, bcur[i], acc[mt][i], 0, 0, 0);
    }
#pragma unroll
    for (int i = 0; i < 4; ++i) bcur[i] = bnxt[i];
  }

  __syncthreads();                         // all waves done reading As rows
  // save As row 0 (the region ep/ww will overwrite); sv is exactly the
  // (t=0, c-pair) uint this thread needs in the context loop
  unsigned sv = ((const unsigned*)As)[tid];
  __syncthreads();                         // saves complete before ep writes

  float* ep = (float*)&As[0][0];           // 256 f32 = As row 0
  float* wwp = (float*)&As[0][0];          // ww[64] reuses ep[0..63] after use

  // ---- epilogue: tanh, dot w_w, cross-wave h-reduction ----
  const float* dpb = dec_proj + b * NHID;
  float pre[4], wv[4];
#pragma unroll
  for (int i = 0; i < 4; ++i) {
    int h = (wave * 4 + i) * 16 + col;
    pre[i] = dpb[h] + b_enc[h];
    wv[i] = w_w[h];
  }
#pragma unroll
  for (int mt = 0; mt < 4; ++mt) {
#pragma unroll
    for (int r = 0; r < 4; ++r) {          // C/D: row = quad*4+r, col = lane&15
      float s = 0.f;
#pragma unroll
      for (int i = 0; i < 4; ++i) {
        float x = acc[mt][i][r] + pre[i];
        float e2 = __expf(2.f * x);        // tanh(x) = 1 - 2/(e^2x+1)
        s += wv[i] * (1.f - 2.f / (e2 + 1.f));
      }
      s += __shfl_xor(s, 1);
      s += __shfl_xor(s, 2);
      s += __shfl_xor(s, 4);
      s += __shfl_xor(s, 8);
      if (col == 0) ep[wave * 64 + mt * 16 + quad * 4 + r] = s;
    }
  }
  __syncthreads();

  // ---- wave 0: energies, block max, exp weights, block sum ----
  if (tid < 64) {
    float e = ep[tid] + ep[64 + tid] + ep[128 + tid] + ep[192 + tid] + w_b[0];
    e_out[b * NT + t0 + tid] = e;          // raw energy (finalize rescales)
    float me = (t0 + tid < len) ? e : -3.0e38f;
    float m = me;
#pragma unroll
    for (int o = 1; o < 64; o <<= 1) m = fmaxf(m, __shfl_xor(m, o));
    float w = __expf(me - m);              // masked t -> 0 exactly
    wwp[tid] = w;                          // overwrites ep[tid] after its read
    float l = w;
#pragma unroll
    for (int o = 1; o < 64; o <<= 1) l += __shfl_xor(l, o);
    if (tid == 0) {
      float* ml = (float*)(ws + WS_ML) + (b * 32 + bx) * 2;
      ml[0] = m; ml[1] = l;
    }
  }
  __syncthreads();

  // ---- context partial from resident bf16 tile: ctx[c] = sum_t w_t*A[t,c] --
  {
    const int c0 = tid * 2;
    const int chunk = c0 >> 3, oc = c0 & 7;
    float w0 = wwp[0];
    float a0 = w0 * blo(sv);               // t=0 from the saved register
    float a1 = w0 * bhi(sv);
#pragma unroll 7
    for (int t = 1; t < 64; ++t) {
      float w = wwp[t];                    // broadcast (same addr all lanes)
      unsigned u = *(const unsigned*)(&As[t][((chunk ^ (t & 7)) << 3) + oc]);
      a0 += w * blo(u);
      a1 += w * bhi(u);
    }
    float2 st = {a0, a1};
    *(float2*)((float*)(ws + WS_CTX) + (size_t)(b * 32 + bx) * NENC + c0) = st;
  }
}

// ------------------------------------------------------------ finalize ------
// one block per b: combine <=32 (m,l,ctx[512]) partials -> att_c;
// rescale stored energies -> att_w.
__global__ __launch_bounds__(256) void finalize_kernel(
    const int* __restrict__ text_len, const char* __restrict__ ws,
    float* __restrict__ d_out)
{
  const int b = blockIdx.x, tid = threadIdx.x;
  const int len = text_len[b];
  const int nv = (len + 63) >> 6;          // valid tiles, 16..32
  __shared__ float sc[32];
  __shared__ float sml[2];

  if (tid < 64) {
    const float* ml = (const float*)(ws + WS_ML) + b * 64;
    float mi = -3.0e38f, li = 0.f;
    if (tid < nv) { mi = ml[tid * 2]; li = ml[tid * 2 + 1]; }
    float m = mi;
#pragma unroll
    for (int o = 1; o < 64; o <<= 1) m = fmaxf(m, __shfl_xor(m, o));
    float e = __expf(mi - m);              // 0 for invalid lanes
    float l = li * e;
#pragma unroll
    for (int o = 1; o < 64; o <<= 1) l += __shfl_xor(l, o);
    if (tid < 32) sc[tid] = e;
    if (tid == 0) { sml[0] = m; sml[1] = l; }
  }
  __syncthreads();
  const float m = sml[0], invl = 1.f / sml[1];

  // att_c[b,c] = sum_i sc[i]*ctx[i][c] / l
  {
    const float* ctx = (const float*)(ws + WS_CTX) + (size_t)b * 32 * NENC;
    float a0 = 0.f, a1 = 0.f;
    for (int i = 0; i < nv; ++i) {
      float s = sc[i];
      a0 += s * ctx[i * NENC + tid];
      a1 += s * ctx[i * NENC + tid + 256];
    }
    d_out[b * NENC + tid] = a0 * invl;
    d_out[b * NENC + tid + 256] = a1 * invl;
  }

  // att_w[b,t] = exp(e_t - m)/l  (0 beyond len)
  float* aw = d_out + NB * NENC + b * NT;
#pragma unroll
  for (int j = 0; j < 8; ++j) {
    int t = tid + j * 256;
    float v = 0.f;
    if (t < len) v = __expf(aw[t] - m) * invl;
    aw[t] = v;
  }
}

// ------------------------------------------------------------------ launch --
extern "C" void kernel_launch(void* const* d_in, const int* in_sizes, int n_in,
                              void* d_out, int out_size, void* d_ws, size_t ws_size,
                              hipStream_t stream)
{
  const float* enc      = (const float*)d_in[0];
  const float* dec_st   = (const float*)d_in[1];
  const float* prev     = (const float*)d_in[2];
  const int*   text_len = (const int*)d_in[3];
  const float* W_enc    = (const float*)d_in[4];
  const float* b_enc    = (const float*)d_in[5];
  const float* W_dec    = (const float*)d_in[6];
  const float* W_att    = (const float*)d_in[7];
  const float* conv_w   = (const float*)d_in[8];
  const float* w_w      = (const float*)d_in[9];
  const float* w_b      = (const float*)d_in[10];
  float* out = (float*)d_out;
  char* ws = (char*)d_ws;

  hipLaunchKernelGGL(prep_kernel, dim3(800), dim3(256), 0, stream,
                     W_enc, W_att, conv_w, dec_st, W_dec, ws);
  hipLaunchKernelGGL(energy_kernel, dim3(32, 64), dim3(256), 0, stream,
                     enc, prev, text_len, b_enc, w_w, w_b, ws, out + NB * NENC);
  hipLaunchKernelGGL(finalize_kernel, dim3(64), dim3(256), 0, stream,
                     text_len, ws, out);
}